// Round 2
// baseline (339.722 us; speedup 1.0000x reference)
//
#include <hip/hip_runtime.h>

#define N_SEQ 1024
#define B_SZ 8
#define C_DIM 256
#define K_HEADS 4
#define FF_DIM 2048

typedef short s16x8 __attribute__((ext_vector_type(8)));
typedef float f32x4v __attribute__((ext_vector_type(4)));

#define GLOAD_LDS16(src, dst)                                                              \
    __builtin_amdgcn_global_load_lds((const __attribute__((address_space(1))) void*)(src), \
                                     (__attribute__((address_space(3))) void*)(dst), 16, 0, 0)

__device__ __forceinline__ unsigned short f2bf(float f) {
    unsigned u = __builtin_bit_cast(unsigned, f);
    u += 0x7FFFu + ((u >> 16) & 1u);
    return (unsigned short)(u >> 16);
}

// ---------------- prep kernels ----------------

__global__ __launch_bounds__(256) void prep_q_kernel(const float* __restrict__ src,
                                                     const float* __restrict__ pos,
                                                     unsigned short* __restrict__ qb) {
    int t = blockIdx.x * 256 + threadIdx.x;
    int i4 = t * 4;
    int n = i4 >> 11;
    int rem = i4 & 2047;
    int b = rem >> 8;
    int c = rem & 255;
    float4 s = *reinterpret_cast<const float4*>(src + i4);
    float4 p = *reinterpret_cast<const float4*>(pos + i4);
    int out = (b * N_SEQ + n) * C_DIM + c;
    *reinterpret_cast<ushort4*>(qb + out) = make_ushort4(
        f2bf((s.x + p.x) * 0.0625f), f2bf((s.y + p.y) * 0.0625f),
        f2bf((s.z + p.z) * 0.0625f), f2bf((s.w + p.w) * 0.0625f));
}

// One block per (k,b,ntile of 64): writes kb row-major (+pos) and vbT transposed [pair][c][n].
__global__ __launch_bounds__(256) void prep_kv_kernel(const float* __restrict__ matched,
                                                      const float* __restrict__ pos,
                                                      unsigned short* __restrict__ kb,
                                                      unsigned short* __restrict__ vbT) {
    __shared__ unsigned short Vl[64][256];
    int blk = blockIdx.x;
    int nt = blk & 15, pr = blk >> 4;          // pr = k*8+b
    int k = pr >> 3, b = pr & 7;
    int n0 = nt * 64;
    int t = threadIdx.x;
    int c4 = (t & 63) * 4;
#pragma unroll
    for (int r = 0; r < 16; r++) {
        int nl = (t >> 6) * 16 + r;
        int n = n0 + nl;
        size_t mi = ((size_t)(k * N_SEQ + n) * B_SZ + b) * C_DIM + c4;
        float4 m = *reinterpret_cast<const float4*>(matched + mi);
        float4 p = *reinterpret_cast<const float4*>(pos + ((size_t)n * B_SZ + b) * C_DIM + c4);
        *reinterpret_cast<ushort4*>(kb + ((size_t)pr * N_SEQ + n) * C_DIM + c4) =
            make_ushort4(f2bf(m.x + p.x), f2bf(m.y + p.y), f2bf(m.z + p.z), f2bf(m.w + p.w));
        *reinterpret_cast<ushort4*>(&Vl[nl][c4]) =
            make_ushort4(f2bf(m.x), f2bf(m.y), f2bf(m.z), f2bf(m.w));
    }
    __syncthreads();
    unsigned short* vrow = vbT + ((size_t)pr * C_DIM + t) * N_SEQ + n0;
#pragma unroll
    for (int g = 0; g < 8; g++) {
        s16x8 v;
#pragma unroll
        for (int j = 0; j < 8; j++) v[j] = (short)Vl[g * 8 + j][t];
        *reinterpret_cast<s16x8*>(vrow + g * 8) = v;
    }
}

__global__ __launch_bounds__(256) void transpose_w_kernel(const float* __restrict__ W,
                                                          unsigned short* __restrict__ Wt,
                                                          int R, int Cn) {
    int idx = blockIdx.x * 256 + threadIdx.x;
    int c = idx / R;
    int r = idx - c * R;
    Wt[idx] = f2bf(W[(size_t)r * Cn + c]);
}

// ---------------- flash attention ----------------
// grid = (K*B)*16 blocks, 256 threads (4 waves, each 16 q-rows, KVBLK=32)
__global__ __launch_bounds__(256) void attn_kernel(const unsigned short* __restrict__ qb,
                                                   const unsigned short* __restrict__ kb,
                                                   const unsigned short* __restrict__ vbT,
                                                   const float* __restrict__ mask,
                                                   unsigned short* __restrict__ att) {
    __shared__ unsigned short Kl[2][32 * 256];   // linear, XOR-swizzled content
    __shared__ unsigned short Pl[4][16][40];

    int blk = blockIdx.x;
    int qt = blk & 15;
    int pr = blk >> 4;
    int kidx = pr >> 3;
    int b = pr & 7;
    int tid = threadIdx.x, wid = tid >> 6, lane = tid & 63;
    int l15 = lane & 15, lg = lane >> 4;
    int q0 = qt * 64 + wid * 16;

    s16x8 qf[8];
    const unsigned short* qrow = qb + ((size_t)(b * N_SEQ + q0 + l15)) * C_DIM + lg * 8;
#pragma unroll
    for (int cc = 0; cc < 8; cc++) qf[cc] = *reinterpret_cast<const s16x8*>(qrow + cc * 32);

    f32x4v oacc[16];
#pragma unroll
    for (int i = 0; i < 16; i++) oacc[i] = (f32x4v){0.f, 0.f, 0.f, 0.f};
    float mrun[4] = {-INFINITY, -INFINITY, -INFINITY, -INFINITY};
    float lrun[4] = {0.f, 0.f, 0.f, 0.f};

    size_t kvbase = (size_t)pr * N_SEQ * C_DIM;
    const unsigned short* kbp = kb + kvbase;
    const float* mbase = mask + ((size_t)b * N_SEQ + q0 + lg * 4) * N_SEQ;

    // K staging: linear dest chunk ch -> row r=ch>>5, src col ((ch&31)*16B) ^ ((r&7)<<4)B
    auto stage_k = [&](int kv0, unsigned short* buf) {
#pragma unroll
        for (int i = 0; i < 4; i++) {
            int ch = (wid * 4 + i) * 64 + lane;
            int r = ch >> 5;
            int ce = ((ch & 31) * 8) ^ ((r & 7) << 3);   // element offset in row
            const unsigned short* src = kbp + (size_t)(kv0 + r) * C_DIM + ce;
            GLOAD_LDS16(src, buf + (wid * 4 + i) * 512);
        }
    };

    stage_k(0, &Kl[0][0]);

    int swz = (l15 & 7) << 3;
    for (int t = 0; t < 32; t++) {
        int cur = t & 1;
        int kv0 = t * 32;
        __syncthreads();                       // K[t] staged; buf^1 free
        if (t + 1 < 32) stage_k(kv0 + 32, &Kl[cur ^ 1][0]);

        // mask loads (issued early, used after QK)
        float mk0[4], mk1[4];
#pragma unroll
        for (int j = 0; j < 4; j++) {
            const float* mr = mbase + (size_t)j * N_SEQ + kv0;
            mk0[j] = mr[l15];
            mk1[j] = mr[16 + l15];
        }
        // V loads (issued early, used in PV; contiguous via vbT)
        s16x8 vreg[16];
#pragma unroll
        for (int ct = 0; ct < 16; ct++)
            vreg[ct] = *reinterpret_cast<const s16x8*>(
                vbT + kvbase + (size_t)(ct * 16 + l15) * N_SEQ + kv0 + lg * 8);

        // S = Q K^T
        f32x4v s0 = {0.f, 0.f, 0.f, 0.f}, s1 = {0.f, 0.f, 0.f, 0.f};
        const unsigned short* KlB = &Kl[cur][0];
#pragma unroll
        for (int cc = 0; cc < 8; cc++) {
            s16x8 k0 = *reinterpret_cast<const s16x8*>(KlB + l15 * 256 + ((cc * 32 + lg * 8) ^ swz));
            s16x8 k1 = *reinterpret_cast<const s16x8*>(KlB + (16 + l15) * 256 + ((cc * 32 + lg * 8) ^ swz));
            s0 = __builtin_amdgcn_mfma_f32_16x16x32_bf16(qf[cc], k0, s0, 0, 0, 0);
            s1 = __builtin_amdgcn_mfma_f32_16x16x32_bf16(qf[cc], k1, s1, 0, 0, 0);
        }
#pragma unroll
        for (int j = 0; j < 4; j++) { s0[j] += mk0[j]; s1[j] += mk1[j]; }

        // online softmax (rows live in 16-lane groups)
        float pm[4], sc[4];
#pragma unroll
        for (int j = 0; j < 4; j++) pm[j] = fmaxf(s0[j], s1[j]);
#pragma unroll
        for (int d = 1; d < 16; d <<= 1) {
#pragma unroll
            for (int j = 0; j < 4; j++) pm[j] = fmaxf(pm[j], __shfl_xor(pm[j], d));
        }
#pragma unroll
        for (int j = 0; j < 4; j++) {
            float mn = fmaxf(mrun[j], pm[j]);
            sc[j] = __expf(mrun[j] - mn);
            mrun[j] = mn;
        }
        float p0[4], p1[4], ps[4];
#pragma unroll
        for (int j = 0; j < 4; j++) {
            p0[j] = __expf(s0[j] - mrun[j]);
            p1[j] = __expf(s1[j] - mrun[j]);
            ps[j] = p0[j] + p1[j];
        }
#pragma unroll
        for (int d = 1; d < 16; d <<= 1) {
#pragma unroll
            for (int j = 0; j < 4; j++) ps[j] += __shfl_xor(ps[j], d);
        }
#pragma unroll
        for (int j = 0; j < 4; j++) lrun[j] = lrun[j] * sc[j] + ps[j];
#pragma unroll
        for (int ct = 0; ct < 16; ct++) {
#pragma unroll
            for (int j = 0; j < 4; j++) oacc[ct][j] *= sc[j];
        }
        // P -> LDS (wave-private: no barrier needed) -> A-fragment
#pragma unroll
        for (int j = 0; j < 4; j++) {
            Pl[wid][lg * 4 + j][l15] = f2bf(p0[j]);
            Pl[wid][lg * 4 + j][16 + l15] = f2bf(p1[j]);
        }
        s16x8 pf = *reinterpret_cast<const s16x8*>(&Pl[wid][l15][lg * 8]);
        // O += P V
#pragma unroll
        for (int ct = 0; ct < 16; ct++)
            oacc[ct] = __builtin_amdgcn_mfma_f32_16x16x32_bf16(pf, vreg[ct], oacc[ct], 0, 0, 0);
    }

    float inv[4];
#pragma unroll
    for (int j = 0; j < 4; j++) inv[j] = 1.0f / lrun[j];
#pragma unroll
    for (int ct = 0; ct < 16; ct++) {
#pragma unroll
        for (int j = 0; j < 4; j++) {
            size_t oi = ((size_t)(b * N_SEQ + q0 + lg * 4 + j)) * (K_HEADS * C_DIM)
                        + kidx * C_DIM + ct * 16 + l15;
            att[oi] = f2bf(oacc[ct][j] * inv[j]);
        }
    }
}

// ---------------- GEMM: C = A(MxK) * Bt(NxK)^T + bias ----------------
// BK=64, double-buffered global_load_lds staging with XOR swizzle.
template <int BM, int BN, int RELU, int OUTBF>
__global__ __launch_bounds__(256) void gemm_bt_kernel(const unsigned short* __restrict__ A,
                                                      const unsigned short* __restrict__ Bt,
                                                      const float* __restrict__ bias,
                                                      float* __restrict__ Cf,
                                                      unsigned short* __restrict__ Cb,
                                                      int M, int Nn, int Kd) {
    constexpr int WAVES_N = (BM == 128) ? 2 : 4;
    constexpr int WN = BN / WAVES_N;       // 64 or 32
    constexpr int NT = WN / 16;            // 4 or 2
    constexpr int TILE = (BM + BN) * 64;   // elems per buffer
    constexpr int CALLS = (BM + BN) / 32;  // gload_lds calls per wave
    __shared__ unsigned short Sl[2][TILE];
    int tm0 = blockIdx.y * BM, tn0 = blockIdx.x * BN;
    int tid = threadIdx.x, wid = tid >> 6, lane = tid & 63;
    int l15 = lane & 15, lg = lane >> 4;
    int wm = (wid / WAVES_N) * 64, wn = (wid % WAVES_N) * WN;

    f32x4v acc[4][NT];
#pragma unroll
    for (int i = 0; i < 4; i++)
#pragma unroll
        for (int j = 0; j < NT; j++) acc[i][j] = (f32x4v){0.f, 0.f, 0.f, 0.f};

    auto stage = [&](int k0, unsigned short* buf) {
#pragma unroll
        for (int i = 0; i < CALLS; i++) {
            int chb = (i * 4 + wid) * 64;   // wave-uniform base chunk
            int ch = chb + lane;
            const unsigned short* src;
            if (chb < BM * 8) {
                int r = ch >> 3;
                int c8 = ((ch & 7) * 8) ^ ((r & 7) << 3);
                src = A + (size_t)(tm0 + r) * Kd + k0 + c8;
            } else {
                int ch2 = ch - BM * 8;
                int r = ch2 >> 3;
                int c8 = ((ch2 & 7) * 8) ^ ((r & 7) << 3);
                src = Bt + (size_t)(tn0 + r) * Kd + k0 + c8;
            }
            GLOAD_LDS16(src, buf + chb * 8);
        }
    };

    stage(0, &Sl[0][0]);
    int nk = Kd >> 6;
    int swz = (l15 & 7) << 3;
    for (int kt = 0; kt < nk; kt++) {
        int cur = kt & 1;
        __syncthreads();
        if (kt + 1 < nk) stage((kt + 1) * 64, &Sl[cur ^ 1][0]);
        const unsigned short* SA = &Sl[cur][0];
        const unsigned short* SB = SA + BM * 64;
        s16x8 af[4][2], bf[NT][2];
#pragma unroll
        for (int mt = 0; mt < 4; mt++)
#pragma unroll
            for (int h = 0; h < 2; h++)
                af[mt][h] = *reinterpret_cast<const s16x8*>(
                    SA + (wm + mt * 16 + l15) * 64 + ((h * 32 + lg * 8) ^ swz));
#pragma unroll
        for (int nt = 0; nt < NT; nt++)
#pragma unroll
            for (int h = 0; h < 2; h++)
                bf[nt][h] = *reinterpret_cast<const s16x8*>(
                    SB + (wn + nt * 16 + l15) * 64 + ((h * 32 + lg * 8) ^ swz));
#pragma unroll
        for (int mt = 0; mt < 4; mt++)
#pragma unroll
            for (int nt = 0; nt < NT; nt++) {
                acc[mt][nt] = __builtin_amdgcn_mfma_f32_16x16x32_bf16(af[mt][0], bf[nt][0], acc[mt][nt], 0, 0, 0);
                acc[mt][nt] = __builtin_amdgcn_mfma_f32_16x16x32_bf16(af[mt][1], bf[nt][1], acc[mt][nt], 0, 0, 0);
            }
    }

#pragma unroll
    for (int mt = 0; mt < 4; mt++) {
#pragma unroll
        for (int nt = 0; nt < NT; nt++) {
#pragma unroll
            for (int j = 0; j < 4; j++) {
                int row = tm0 + wm + mt * 16 + lg * 4 + j;
                int col = tn0 + wn + nt * 16 + l15;
                float v = acc[mt][nt][j] + bias[col];
                if (RELU) v = fmaxf(v, 0.f);
                if (OUTBF) Cb[(size_t)row * Nn + col] = f2bf(v);
                else       Cf[(size_t)row * Nn + col] = v;
            }
        }
    }
}

// ---------------- fused residual + LayerNorm ----------------
__global__ __launch_bounds__(256) void ln1_kernel(const float* __restrict__ src,
                                                  const float* __restrict__ recT,
                                                  const float* __restrict__ g,
                                                  const float* __restrict__ be,
                                                  float* __restrict__ outf,
                                                  unsigned short* __restrict__ outb) {
    int r = blockIdx.x * 4 + (threadIdx.x >> 6);
    int lane = threadIdx.x & 63;
    int n = r >> 3, b = r & 7;
    int c = lane * 4;
    float4 xs = *reinterpret_cast<const float4*>(src + (size_t)r * C_DIM + c);
    float4 xr = *reinterpret_cast<const float4*>(recT + ((size_t)(b * N_SEQ + n)) * C_DIM + c);
    float x[4] = {xs.x + xr.x, xs.y + xr.y, xs.z + xr.z, xs.w + xr.w};
    float s = x[0] + x[1] + x[2] + x[3];
    float q = x[0] * x[0] + x[1] * x[1] + x[2] * x[2] + x[3] * x[3];
#pragma unroll
    for (int d = 1; d < 64; d <<= 1) {
        s += __shfl_xor(s, d);
        q += __shfl_xor(q, d);
    }
    float mean = s * (1.f / 256.f);
    float var = q * (1.f / 256.f) - mean * mean;
    float rstd = rsqrtf(var + 1e-5f);
    float4 gv = *reinterpret_cast<const float4*>(g + c);
    float4 bv = *reinterpret_cast<const float4*>(be + c);
    float y0 = (x[0] - mean) * rstd * gv.x + bv.x;
    float y1 = (x[1] - mean) * rstd * gv.y + bv.y;
    float y2 = (x[2] - mean) * rstd * gv.z + bv.z;
    float y3 = (x[3] - mean) * rstd * gv.w + bv.w;
    *reinterpret_cast<float4*>(outf + (size_t)r * C_DIM + c) = make_float4(y0, y1, y2, y3);
    *reinterpret_cast<ushort4*>(outb + (size_t)r * C_DIM + c) =
        make_ushort4(f2bf(y0), f2bf(y1), f2bf(y2), f2bf(y3));
}

__global__ __launch_bounds__(256) void ln2_kernel(const float* __restrict__ rec1f,
                                                  const float* __restrict__ ffn,
                                                  const float* __restrict__ g,
                                                  const float* __restrict__ be,
                                                  float* __restrict__ out) {
    int r = blockIdx.x * 4 + (threadIdx.x >> 6);
    int lane = threadIdx.x & 63;
    int c = lane * 4;
    size_t base = (size_t)r * C_DIM + c;
    float4 xa = *reinterpret_cast<const float4*>(rec1f + base);
    float4 xb = *reinterpret_cast<const float4*>(ffn + base);
    float x[4] = {xa.x + xb.x, xa.y + xb.y, xa.z + xb.z, xa.w + xb.w};
    float s = x[0] + x[1] + x[2] + x[3];
    float q = x[0] * x[0] + x[1] * x[1] + x[2] * x[2] + x[3] * x[3];
#pragma unroll
    for (int d = 1; d < 64; d <<= 1) {
        s += __shfl_xor(s, d);
        q += __shfl_xor(q, d);
    }
    float mean = s * (1.f / 256.f);
    float var = q * (1.f / 256.f) - mean * mean;
    float rstd = rsqrtf(var + 1e-5f);
    float4 gv = *reinterpret_cast<const float4*>(g + c);
    float4 bv = *reinterpret_cast<const float4*>(be + c);
    *reinterpret_cast<float4*>(out + base) = make_float4(
        (x[0] - mean) * rstd * gv.x + bv.x,
        (x[1] - mean) * rstd * gv.y + bv.y,
        (x[2] - mean) * rstd * gv.z + bv.z,
        (x[3] - mean) * rstd * gv.w + bv.w);
}

// ---------------- launch ----------------

extern "C" void kernel_launch(void* const* d_in, const int* in_sizes, int n_in,
                              void* d_out, int out_size, void* d_ws, size_t ws_size,
                              hipStream_t stream) {
    const float* src   = (const float*)d_in[0];
    const float* match = (const float*)d_in[1];
    const float* pos   = (const float*)d_in[2];
    const float* mask  = (const float*)d_in[3];
    const float* Wagg  = (const float*)d_in[4];
    const float* bagg  = (const float*)d_in[5];
    const float* W1    = (const float*)d_in[6];
    const float* b1    = (const float*)d_in[7];
    const float* W2    = (const float*)d_in[8];
    const float* b2    = (const float*)d_in[9];
    const float* g1    = (const float*)d_in[10];
    const float* be1   = (const float*)d_in[11];
    const float* g2    = (const float*)d_in[12];
    const float* be2   = (const float*)d_in[13];

    char* ws = (char*)d_ws;
    unsigned short* qb    = (unsigned short*)(ws + 0);          //  4 MB (B,N,C) bf16 pre-scaled
    unsigned short* kb    = (unsigned short*)(ws + 4194304);    // 16 MB (K*B,N,C) bf16
    unsigned short* vbT   = (unsigned short*)(ws + 20971520);   // 16 MB (K*B,C,N) bf16 transposed
    unsigned short* att   = (unsigned short*)(ws + 37748736);   // 16 MB (B,N,K*C) bf16
    unsigned short* WaggT = (unsigned short*)(ws + 54525952);   // 0.5 MB
    unsigned short* W1T   = (unsigned short*)(ws + 55050240);   // 1 MB
    unsigned short* W2T   = (unsigned short*)(ws + 56098816);   // 1 MB
    float*          rec_t = (float*)(ws + 57147392);            // 8 MB (B*N,C) f32
    float*          rec1f = (float*)(ws + 65536000);            // 8 MB (N*B,C) f32
    unsigned short* rec1b = (unsigned short*)(ws + 73924608);   // 4 MB bf16
    unsigned short* hid   = (unsigned short*)(ws + 4194304);    // 32 MB, aliases kb+vbT (dead)
    float*          ffn   = (float*)(ws + 57147392);            // 8 MB, aliases rec_t (dead)
    float* outp = (float*)d_out;

    prep_q_kernel<<<2048, 256, 0, stream>>>(src, pos, qb);
    prep_kv_kernel<<<512, 256, 0, stream>>>(match, pos, kb, vbT);
    transpose_w_kernel<<<1024, 256, 0, stream>>>(Wagg, WaggT, K_HEADS * C_DIM, C_DIM);
    transpose_w_kernel<<<2048, 256, 0, stream>>>(W1, W1T, C_DIM, FF_DIM);
    transpose_w_kernel<<<2048, 256, 0, stream>>>(W2, W2T, FF_DIM, C_DIM);

    attn_kernel<<<K_HEADS * B_SZ * (N_SEQ / 64), 256, 0, stream>>>(qb, kb, vbT, mask, att);

    // rec_t(B*N,C) = att(B*N, K*C) @ WaggT^T + bagg
    gemm_bt_kernel<64, 128, 0, 0><<<dim3(2, 128), 256, 0, stream>>>(
        att, WaggT, bagg, rec_t, nullptr, B_SZ * N_SEQ, C_DIM, K_HEADS * C_DIM);
    ln1_kernel<<<2048, 256, 0, stream>>>(src, rec_t, g1, be1, rec1f, rec1b);
    // hid = relu(rec1 @ W1 + b1)
    gemm_bt_kernel<128, 128, 1, 1><<<dim3(16, 64), 256, 0, stream>>>(
        rec1b, W1T, b1, nullptr, hid, N_SEQ * B_SZ, FF_DIM, C_DIM);
    // ffn = hid @ W2 + b2
    gemm_bt_kernel<64, 128, 0, 0><<<dim3(2, 128), 256, 0, stream>>>(
        hid, W2T, b2, ffn, nullptr, N_SEQ * B_SZ, C_DIM, FF_DIM);
    ln2_kernel<<<2048, 256, 0, stream>>>(rec1f, ffn, g2, be2, outp);
}

// Round 3
// 219.304 us; speedup vs baseline: 1.5491x; 1.5491x over previous
//
#include <hip/hip_runtime.h>

#define N_SEQ 1024
#define B_SZ 8
#define C_DIM 256
#define K_HEADS 4
#define FF_DIM 2048

typedef short s16x8 __attribute__((ext_vector_type(8)));
typedef float f32x4v __attribute__((ext_vector_type(4)));

#define GLOAD_LDS16(src, dst)                                                              \
    __builtin_amdgcn_global_load_lds((const __attribute__((address_space(1))) void*)(src), \
                                     (__attribute__((address_space(3))) void*)(dst), 16, 0, 0)

__device__ __forceinline__ unsigned short f2bf(float f) {
    unsigned u = __builtin_bit_cast(unsigned, f);
    u += 0x7FFFu + ((u >> 16) & 1u);
    return (unsigned short)(u >> 16);
}

// ---------------- prep kernels ----------------

__global__ __launch_bounds__(256) void prep_q_kernel(const float* __restrict__ src,
                                                     const float* __restrict__ pos,
                                                     unsigned short* __restrict__ qb) {
    int t = blockIdx.x * 256 + threadIdx.x;
    int i4 = t * 4;
    int n = i4 >> 11;
    int rem = i4 & 2047;
    int b = rem >> 8;
    int c = rem & 255;
    float4 s = *reinterpret_cast<const float4*>(src + i4);
    float4 p = *reinterpret_cast<const float4*>(pos + i4);
    int out = (b * N_SEQ + n) * C_DIM + c;
    *reinterpret_cast<ushort4*>(qb + out) = make_ushort4(
        f2bf((s.x + p.x) * 0.0625f), f2bf((s.y + p.y) * 0.0625f),
        f2bf((s.z + p.z) * 0.0625f), f2bf((s.w + p.w) * 0.0625f));
}

// One block per (k,b,ntile of 64): writes kb row-major (+pos) and vbT transposed [pair][c][n].
__global__ __launch_bounds__(256) void prep_kv_kernel(const float* __restrict__ matched,
                                                      const float* __restrict__ pos,
                                                      unsigned short* __restrict__ kb,
                                                      unsigned short* __restrict__ vbT) {
    __shared__ unsigned short Vl[64][256];
    int blk = blockIdx.x;
    int nt = blk & 15, pr = blk >> 4;          // pr = k*8+b
    int k = pr >> 3, b = pr & 7;
    int n0 = nt * 64;
    int t = threadIdx.x;
    int c4 = (t & 63) * 4;
#pragma unroll
    for (int r = 0; r < 16; r++) {
        int nl = (t >> 6) * 16 + r;
        int n = n0 + nl;
        size_t mi = ((size_t)(k * N_SEQ + n) * B_SZ + b) * C_DIM + c4;
        float4 m = *reinterpret_cast<const float4*>(matched + mi);
        float4 p = *reinterpret_cast<const float4*>(pos + ((size_t)n * B_SZ + b) * C_DIM + c4);
        *reinterpret_cast<ushort4*>(kb + ((size_t)pr * N_SEQ + n) * C_DIM + c4) =
            make_ushort4(f2bf(m.x + p.x), f2bf(m.y + p.y), f2bf(m.z + p.z), f2bf(m.w + p.w));
        *reinterpret_cast<ushort4*>(&Vl[nl][c4]) =
            make_ushort4(f2bf(m.x), f2bf(m.y), f2bf(m.z), f2bf(m.w));
    }
    __syncthreads();
    unsigned short* vrow = vbT + ((size_t)pr * C_DIM + t) * N_SEQ + n0;
#pragma unroll
    for (int g = 0; g < 8; g++) {
        s16x8 v;
#pragma unroll
        for (int j = 0; j < 8; j++) v[j] = (short)Vl[g * 8 + j][t];
        *reinterpret_cast<s16x8*>(vrow + g * 8) = v;
    }
}

__global__ __launch_bounds__(256) void transpose_w_kernel(const float* __restrict__ W,
                                                          unsigned short* __restrict__ Wt,
                                                          int R, int Cn) {
    int idx = blockIdx.x * 256 + threadIdx.x;
    int c = idx / R;
    int r = idx - c * R;
    Wt[idx] = f2bf(W[(size_t)r * Cn + c]);
}

// ---------------- flash attention ----------------
// grid = (K*B)*16 blocks, 256 threads (4 waves, each 16 q-rows, KVBLK=32).
// S^T = K·Q^T orientation; O^T = V^T·P^T orientation.
__global__ __launch_bounds__(256) void attn_kernel(const unsigned short* __restrict__ qb,
                                                   const unsigned short* __restrict__ kb,
                                                   const unsigned short* __restrict__ vbT,
                                                   const float* __restrict__ mask,
                                                   unsigned short* __restrict__ att) {
    __shared__ unsigned short Kl[2][32 * 256];   // linear, XOR-swizzled content (gload_lds)
    __shared__ unsigned short Vl[256][40];       // V^T tile, padded rows (80B) -> conflict-free
    __shared__ unsigned short Pl[4][16][40];     // wave-private P

    int blk = blockIdx.x;
    int qt = blk & 15;
    int pr = blk >> 4;
    int kidx = pr >> 3;
    int b = pr & 7;
    int tid = threadIdx.x, wid = tid >> 6, lane = tid & 63;
    int l15 = lane & 15, lg = lane >> 4;
    int q0 = qt * 64 + wid * 16;                 // wave's q base; this lane's q = q0 + l15

    // Q fragments (used as B-operand; per-lane layout identical to A): Q[q0+l15][cc*32+lg*8+i]
    s16x8 qf[8];
    const unsigned short* qrow = qb + ((size_t)(b * N_SEQ + q0 + l15)) * C_DIM + lg * 8;
#pragma unroll
    for (int cc = 0; cc < 8; cc++) qf[cc] = *reinterpret_cast<const s16x8*>(qrow + cc * 32);

    // O^T accumulator: oacc[ct][j] = O^T[c = ct*16 + lg*4 + j][q = l15]
    f32x4v oacc[16];
#pragma unroll
    for (int i = 0; i < 16; i++) oacc[i] = (f32x4v){0.f, 0.f, 0.f, 0.f};
    float mrun = -3e38f, lrun = 0.f;

    size_t kvbase = (size_t)pr * N_SEQ * C_DIM;
    const unsigned short* kbp = kb + kvbase;
    const unsigned short* vtp = vbT + ((size_t)pr * C_DIM + tid) * N_SEQ;  // this thread's V^T row
    const float* mbase = mask + ((size_t)b * N_SEQ + q0 + l15) * N_SEQ;    // this lane's mask row

    auto stage_k = [&](int kv0, unsigned short* buf) {
#pragma unroll
        for (int i = 0; i < 4; i++) {
            int ch = (wid * 4 + i) * 64 + lane;
            int r = ch >> 5;
            int ce = ((ch & 31) * 8) ^ ((r & 7) << 3);
            GLOAD_LDS16(kbp + (size_t)(kv0 + r) * C_DIM + ce, &buf[(wid * 4 + i) * 512]);
        }
    };

    s16x8 vr[4];
    stage_k(0, &Kl[0][0]);
#pragma unroll
    for (int c = 0; c < 4; c++) vr[c] = *reinterpret_cast<const s16x8*>(vtp + c * 8);

    int swz = (l15 & 7) << 3;
    for (int t = 0; t < 32; t++) {
        int cur = t & 1;
        int kv0 = t * 32;
        __syncthreads();                         // (A) K[t] in LDS; Vl free; vr[t] arrived
        // write V^T tile rows (thread t owns channel row tid)
#pragma unroll
        for (int c = 0; c < 4; c++)
            *reinterpret_cast<s16x8*>(&Vl[tid][c * 8]) = vr[c];

        // mask loads (coalesced float4; used after QK)
        f32x4v m0 = *reinterpret_cast<const f32x4v*>(mbase + kv0 + lg * 4);
        f32x4v m1 = *reinterpret_cast<const f32x4v*>(mbase + kv0 + 16 + lg * 4);

        // S^T = K Q^T : rows = kv (ct*16 + lg*4 + j), cols = q (l15)
        f32x4v s0 = {0.f, 0.f, 0.f, 0.f}, s1 = {0.f, 0.f, 0.f, 0.f};
        const unsigned short* KlB = &Kl[cur][0];
#pragma unroll
        for (int cc = 0; cc < 8; cc++) {
            s16x8 k0 = *reinterpret_cast<const s16x8*>(KlB + l15 * 256 + ((cc * 32 + lg * 8) ^ swz));
            s16x8 k1 = *reinterpret_cast<const s16x8*>(KlB + (16 + l15) * 256 + ((cc * 32 + lg * 8) ^ swz));
            s0 = __builtin_amdgcn_mfma_f32_16x16x32_bf16(k0, qf[cc], s0, 0, 0, 0);
            s1 = __builtin_amdgcn_mfma_f32_16x16x32_bf16(k1, qf[cc], s1, 0, 0, 0);
        }
#pragma unroll
        for (int j = 0; j < 4; j++) { s0[j] += m0[j]; s1[j] += m1[j]; }

        // softmax over kv: in-lane reduce (8 vals) + cross-group (xor 16, 32)
        float pm = fmaxf(fmaxf(fmaxf(s0[0], s0[1]), fmaxf(s0[2], s0[3])),
                         fmaxf(fmaxf(s1[0], s1[1]), fmaxf(s1[2], s1[3])));
        pm = fmaxf(pm, __shfl_xor(pm, 16));
        pm = fmaxf(pm, __shfl_xor(pm, 32));
        if (__any(pm > mrun + 8.f)) {            // defer-max: rescale only when needed
            float mn = fmaxf(mrun, pm);
            float sc = __expf(mrun - mn);
            mrun = mn;
            lrun *= sc;
#pragma unroll
            for (int ct = 0; ct < 16; ct++)
#pragma unroll
                for (int j = 0; j < 4; j++) oacc[ct][j] *= sc;
        }
        float p0[4], p1[4];
#pragma unroll
        for (int j = 0; j < 4; j++) {
            p0[j] = __expf(s0[j] - mrun);
            p1[j] = __expf(s1[j] - mrun);
        }
        float ps = (p0[0] + p0[1]) + (p0[2] + p0[3]) + (p1[0] + p1[1]) + (p1[2] + p1[3]);
        ps += __shfl_xor(ps, 16);
        ps += __shfl_xor(ps, 32);
        lrun += ps;

        __syncthreads();                         // (B) Vl writes visible to all waves

        // prefetch next tile (issued AFTER (B) so no barrier drains it; covered by PV)
        if (t + 1 < 32) {
            stage_k(kv0 + 32, &Kl[cur ^ 1][0]);
#pragma unroll
            for (int c = 0; c < 4; c++)
                vr[c] = *reinterpret_cast<const s16x8*>(vtp + kv0 + 32 + c * 8);
        }

        // P^T (rows kv, cols q) -> Pl[wid][q][kv] (wave-private, no barrier)
        *reinterpret_cast<ushort4*>(&Pl[wid][l15][lg * 4]) =
            make_ushort4(f2bf(p0[0]), f2bf(p0[1]), f2bf(p0[2]), f2bf(p0[3]));
        *reinterpret_cast<ushort4*>(&Pl[wid][l15][16 + lg * 4]) =
            make_ushort4(f2bf(p1[0]), f2bf(p1[1]), f2bf(p1[2]), f2bf(p1[3]));
        s16x8 pf = *reinterpret_cast<const s16x8*>(&Pl[wid][l15][lg * 8]);

        // O^T += V^T P^T : A = V^T rows (channels), B = P^T
#pragma unroll
        for (int ct = 0; ct < 16; ct++) {
            s16x8 af = *reinterpret_cast<const s16x8*>(&Vl[ct * 16 + l15][lg * 8]);
            oacc[ct] = __builtin_amdgcn_mfma_f32_16x16x32_bf16(af, pf, oacc[ct], 0, 0, 0);
        }
    }

    float inv = 1.0f / lrun;                     // per-lane: q = l15
    size_t orow = ((size_t)(b * N_SEQ + q0 + l15)) * (K_HEADS * C_DIM) + kidx * C_DIM + lg * 4;
#pragma unroll
    for (int ct = 0; ct < 16; ct++) {
        *reinterpret_cast<ushort4*>(att + orow + ct * 16) =
            make_ushort4(f2bf(oacc[ct][0] * inv), f2bf(oacc[ct][1] * inv),
                         f2bf(oacc[ct][2] * inv), f2bf(oacc[ct][3] * inv));
    }
}

// ---------------- GEMM: C = A(MxK) * Bt(NxK)^T + bias ----------------
template <int BM, int BN, int RELU, int OUTBF>
__global__ __launch_bounds__(256) void gemm_bt_kernel(const unsigned short* __restrict__ A,
                                                      const unsigned short* __restrict__ Bt,
                                                      const float* __restrict__ bias,
                                                      float* __restrict__ Cf,
                                                      unsigned short* __restrict__ Cb,
                                                      int M, int Nn, int Kd) {
    constexpr int WAVES_N = (BM == 128) ? 2 : 4;
    constexpr int WN = BN / WAVES_N;
    constexpr int NT = WN / 16;
    constexpr int TILE = (BM + BN) * 64;
    constexpr int CALLS = (BM + BN) / 32;
    __shared__ unsigned short Sl[2][TILE];
    int tm0 = blockIdx.y * BM, tn0 = blockIdx.x * BN;
    int tid = threadIdx.x, wid = tid >> 6, lane = tid & 63;
    int l15 = lane & 15, lg = lane >> 4;
    int wm = (wid / WAVES_N) * 64, wn = (wid % WAVES_N) * WN;

    f32x4v acc[4][NT];
#pragma unroll
    for (int i = 0; i < 4; i++)
#pragma unroll
        for (int j = 0; j < NT; j++) acc[i][j] = (f32x4v){0.f, 0.f, 0.f, 0.f};

    auto stage = [&](int k0, unsigned short* buf) {
#pragma unroll
        for (int i = 0; i < CALLS; i++) {
            int chb = (i * 4 + wid) * 64;
            int ch = chb + lane;
            const unsigned short* src;
            if (chb < BM * 8) {
                int r = ch >> 3;
                int c8 = ((ch & 7) * 8) ^ ((r & 7) << 3);
                src = A + (size_t)(tm0 + r) * Kd + k0 + c8;
            } else {
                int ch2 = ch - BM * 8;
                int r = ch2 >> 3;
                int c8 = ((ch2 & 7) * 8) ^ ((r & 7) << 3);
                src = Bt + (size_t)(tn0 + r) * Kd + k0 + c8;
            }
            GLOAD_LDS16(src, buf + chb * 8);
        }
    };

    stage(0, &Sl[0][0]);
    int nk = Kd >> 6;
    int swz = (l15 & 7) << 3;
    for (int kt = 0; kt < nk; kt++) {
        int cur = kt & 1;
        __syncthreads();
        if (kt + 1 < nk) stage((kt + 1) * 64, &Sl[cur ^ 1][0]);
        const unsigned short* SA = &Sl[cur][0];
        const unsigned short* SB = SA + BM * 64;
        s16x8 af[4][2], bf[NT][2];
#pragma unroll
        for (int mt = 0; mt < 4; mt++)
#pragma unroll
            for (int h = 0; h < 2; h++)
                af[mt][h] = *reinterpret_cast<const s16x8*>(
                    SA + (wm + mt * 16 + l15) * 64 + ((h * 32 + lg * 8) ^ swz));
#pragma unroll
        for (int nt = 0; nt < NT; nt++)
#pragma unroll
            for (int h = 0; h < 2; h++)
                bf[nt][h] = *reinterpret_cast<const s16x8*>(
                    SB + (wn + nt * 16 + l15) * 64 + ((h * 32 + lg * 8) ^ swz));
#pragma unroll
        for (int mt = 0; mt < 4; mt++)
#pragma unroll
            for (int nt = 0; nt < NT; nt++) {
                acc[mt][nt] = __builtin_amdgcn_mfma_f32_16x16x32_bf16(af[mt][0], bf[nt][0], acc[mt][nt], 0, 0, 0);
                acc[mt][nt] = __builtin_amdgcn_mfma_f32_16x16x32_bf16(af[mt][1], bf[nt][1], acc[mt][nt], 0, 0, 0);
            }
    }

#pragma unroll
    for (int mt = 0; mt < 4; mt++) {
#pragma unroll
        for (int nt = 0; nt < NT; nt++) {
#pragma unroll
            for (int j = 0; j < 4; j++) {
                int row = tm0 + wm + mt * 16 + lg * 4 + j;
                int col = tn0 + wn + nt * 16 + l15;
                float v = acc[mt][nt][j] + bias[col];
                if (RELU) v = fmaxf(v, 0.f);
                if (OUTBF) Cb[(size_t)row * Nn + col] = f2bf(v);
                else       Cf[(size_t)row * Nn + col] = v;
            }
        }
    }
}

// ---------------- fused residual + LayerNorm ----------------
__global__ __launch_bounds__(256) void ln1_kernel(const float* __restrict__ src,
                                                  const float* __restrict__ recT,
                                                  const float* __restrict__ g,
                                                  const float* __restrict__ be,
                                                  float* __restrict__ outf,
                                                  unsigned short* __restrict__ outb) {
    int r = blockIdx.x * 4 + (threadIdx.x >> 6);
    int lane = threadIdx.x & 63;
    int n = r >> 3, b = r & 7;
    int c = lane * 4;
    float4 xs = *reinterpret_cast<const float4*>(src + (size_t)r * C_DIM + c);
    float4 xr = *reinterpret_cast<const float4*>(recT + ((size_t)(b * N_SEQ + n)) * C_DIM + c);
    float x[4] = {xs.x + xr.x, xs.y + xr.y, xs.z + xr.z, xs.w + xr.w};
    float s = x[0] + x[1] + x[2] + x[3];
    float q = x[0] * x[0] + x[1] * x[1] + x[2] * x[2] + x[3] * x[3];
#pragma unroll
    for (int d = 1; d < 64; d <<= 1) {
        s += __shfl_xor(s, d);
        q += __shfl_xor(q, d);
    }
    float mean = s * (1.f / 256.f);
    float var = q * (1.f / 256.f) - mean * mean;
    float rstd = rsqrtf(var + 1e-5f);
    float4 gv = *reinterpret_cast<const float4*>(g + c);
    float4 bv = *reinterpret_cast<const float4*>(be + c);
    float y0 = (x[0] - mean) * rstd * gv.x + bv.x;
    float y1 = (x[1] - mean) * rstd * gv.y + bv.y;
    float y2 = (x[2] - mean) * rstd * gv.z + bv.z;
    float y3 = (x[3] - mean) * rstd * gv.w + bv.w;
    *reinterpret_cast<float4*>(outf + (size_t)r * C_DIM + c) = make_float4(y0, y1, y2, y3);
    *reinterpret_cast<ushort4*>(outb + (size_t)r * C_DIM + c) =
        make_ushort4(f2bf(y0), f2bf(y1), f2bf(y2), f2bf(y3));
}

__global__ __launch_bounds__(256) void ln2_kernel(const float* __restrict__ rec1f,
                                                  const float* __restrict__ ffn,
                                                  const float* __restrict__ g,
                                                  const float* __restrict__ be,
                                                  float* __restrict__ out) {
    int r = blockIdx.x * 4 + (threadIdx.x >> 6);
    int lane = threadIdx.x & 63;
    int c = lane * 4;
    size_t base = (size_t)r * C_DIM + c;
    float4 xa = *reinterpret_cast<const float4*>(rec1f + base);
    float4 xb = *reinterpret_cast<const float4*>(ffn + base);
    float x[4] = {xa.x + xb.x, xa.y + xb.y, xa.z + xb.z, xa.w + xb.w};
    float s = x[0] + x[1] + x[2] + x[3];
    float q = x[0] * x[0] + x[1] * x[1] + x[2] * x[2] + x[3] * x[3];
#pragma unroll
    for (int d = 1; d < 64; d <<= 1) {
        s += __shfl_xor(s, d);
        q += __shfl_xor(q, d);
    }
    float mean = s * (1.f / 256.f);
    float var = q * (1.f / 256.f) - mean * mean;
    float rstd = rsqrtf(var + 1e-5f);
    float4 gv = *reinterpret_cast<const float4*>(g + c);
    float4 bv = *reinterpret_cast<const float4*>(be + c);
    *reinterpret_cast<float4*>(out + base) = make_float4(
        (x[0] - mean) * rstd * gv.x + bv.x,
        (x[1] - mean) * rstd * gv.y + bv.y,
        (x[2] - mean) * rstd * gv.z + bv.z,
        (x[3] - mean) * rstd * gv.w + bv.w);
}

// ---------------- launch ----------------

extern "C" void kernel_launch(void* const* d_in, const int* in_sizes, int n_in,
                              void* d_out, int out_size, void* d_ws, size_t ws_size,
                              hipStream_t stream) {
    const float* src   = (const float*)d_in[0];
    const float* match = (const float*)d_in[1];
    const float* pos   = (const float*)d_in[2];
    const float* mask  = (const float*)d_in[3];
    const float* Wagg  = (const float*)d_in[4];
    const float* bagg  = (const float*)d_in[5];
    const float* W1    = (const float*)d_in[6];
    const float* b1    = (const float*)d_in[7];
    const float* W2    = (const float*)d_in[8];
    const float* b2    = (const float*)d_in[9];
    const float* g1    = (const float*)d_in[10];
    const float* be1   = (const float*)d_in[11];
    const float* g2    = (const float*)d_in[12];
    const float* be2   = (const float*)d_in[13];

    char* ws = (char*)d_ws;
    unsigned short* qb    = (unsigned short*)(ws + 0);          //  4 MB (B,N,C) bf16 pre-scaled
    unsigned short* kb    = (unsigned short*)(ws + 4194304);    // 16 MB (K*B,N,C) bf16
    unsigned short* vbT   = (unsigned short*)(ws + 20971520);   // 16 MB (K*B,C,N) bf16 transposed
    unsigned short* att   = (unsigned short*)(ws + 37748736);   // 16 MB (B,N,K*C) bf16
    unsigned short* WaggT = (unsigned short*)(ws + 54525952);   // 0.5 MB
    unsigned short* W1T   = (unsigned short*)(ws + 55050240);   // 1 MB
    unsigned short* W2T   = (unsigned short*)(ws + 56098816);   // 1 MB
    float*          rec_t = (float*)(ws + 57147392);            // 8 MB (B*N,C) f32
    float*          rec1f = (float*)(ws + 65536000);            // 8 MB (N*B,C) f32
    unsigned short* rec1b = (unsigned short*)(ws + 73924608);   // 4 MB bf16
    unsigned short* hid   = (unsigned short*)(ws + 4194304);    // 32 MB, aliases kb+vbT (dead)
    float*          ffn   = (float*)(ws + 57147392);            // 8 MB, aliases rec_t (dead)
    float* outp = (float*)d_out;

    prep_q_kernel<<<2048, 256, 0, stream>>>(src, pos, qb);
    prep_kv_kernel<<<512, 256, 0, stream>>>(match, pos, kb, vbT);
    transpose_w_kernel<<<1024, 256, 0, stream>>>(Wagg, WaggT, K_HEADS * C_DIM, C_DIM);
    transpose_w_kernel<<<2048, 256, 0, stream>>>(W1, W1T, C_DIM, FF_DIM);
    transpose_w_kernel<<<2048, 256, 0, stream>>>(W2, W2T, FF_DIM, C_DIM);

    attn_kernel<<<K_HEADS * B_SZ * (N_SEQ / 64), 256, 0, stream>>>(qb, kb, vbT, mask, att);

    gemm_bt_kernel<64, 128, 0, 0><<<dim3(2, 128), 256, 0, stream>>>(
        att, WaggT, bagg, rec_t, nullptr, B_SZ * N_SEQ, C_DIM, K_HEADS * C_DIM);
    ln1_kernel<<<2048, 256, 0, stream>>>(src, rec_t, g1, be1, rec1f, rec1b);
    gemm_bt_kernel<128, 128, 1, 1><<<dim3(16, 64), 256, 0, stream>>>(
        rec1b, W1T, b1, nullptr, hid, N_SEQ * B_SZ, FF_DIM, C_DIM);
    gemm_bt_kernel<64, 128, 0, 0><<<dim3(2, 128), 256, 0, stream>>>(
        hid, W2T, b2, ffn, nullptr, N_SEQ * B_SZ, C_DIM, FF_DIM);
    ln2_kernel<<<2048, 256, 0, stream>>>(rec1f, ffn, g2, be2, outp);
}